// Round 8
// baseline (142.027 us; speedup 1.0000x reference)
//
#include <hip/hip_runtime.h>

#define CD_B 4
#define CD_NPTS 4096
#define CD_TOTAL (CD_B * CD_NPTS)   // 16384 points per array

// Build (x, y, z, |p|^2) float4 arrays in d_ws for both inputs; zero out[0].
// 128 blocks x 256 threads covers 32768 points.
__global__ __launch_bounds__(256) void cd_prep(const float* __restrict__ recon,
                                               const float* __restrict__ gt,
                                               float4* __restrict__ pts4,
                                               float* __restrict__ out) {
    const int i = blockIdx.x * 256 + threadIdx.x;   // [0, 32768)
    if (i == 0) out[0] = 0.f;
    const int idx = i & (CD_TOTAL - 1);             // [0, 16384)
    const float* src = (i < CD_TOTAL) ? recon : gt;
    const float x = src[idx * 3 + 0];
    const float y = src[idx * 3 + 1];
    const float z = src[idx * 3 + 2];
    pts4[i] = make_float4(x, y, z, fmaf(z, z, fmaf(y, y, x * x)));
}

// 512 blocks x 256 threads: bid = dir(2) x batch(4) x point-group(64).
// Block owns 64 points (one per lane, same 64 for all 4 waves); wave w streams
// the opposite set's quarter [1024w, 1024w+1024) via wave-uniform float4 loads
// (uniform address -> s_load into SGPRs: inner 2-point step = 7 VALU + 1 SMEM,
// no LDS, no barriers). dist via |p-g|^2 = |p|^2 + (|g|^2 - 2 p.g).
// Epilogue: LDS combine of the 4 quarter-partials (1 barrier), add |p|^2,
// clamp, 64-lane butterfly sum, one atomicAdd per block.
__global__ __launch_bounds__(256) void cd_main(const float4* __restrict__ pts4,
                                               float* __restrict__ out) {
    const int bid = blockIdx.x;
    const int dir = bid >> 8;          // 0: rowmin (recon->gt), 1: colmin
    const int b   = (bid >> 6) & 3;
    const int pg  = bid & 63;
    const int t   = threadIdx.x;
    const int l   = t & 63;
    const int w   = __builtin_amdgcn_readfirstlane(t >> 6);  // wave id, uniform

    const float4* rs4 = pts4;              // recon (x,y,z,norm)
    const float4* gs4 = pts4 + CD_TOTAL;   // gt
    const float4* own    = (dir == 0 ? rs4 : gs4) + b * CD_NPTS + pg * 64;
    const float4* stream = (dir == 0 ? gs4 : rs4) + b * CD_NPTS + w * 1024;

    const float4 p = own[l];               // per-lane owned point
    const float ax = -2.f * p.x, ay = -2.f * p.y, az = -2.f * p.z;

    float m = __builtin_inff();
    #pragma unroll 4
    for (int j = 0; j < 1024; j += 2) {
        const float4 g0 = stream[j];       // uniform -> SGPR load
        const float4 g1 = stream[j + 1];
        const float d0 = fmaf(ax, g0.x, fmaf(ay, g0.y, fmaf(az, g0.z, g0.w)));
        const float d1 = fmaf(ax, g1.x, fmaf(ay, g1.y, fmaf(az, g1.z, g1.w)));
        m = fminf(fminf(d0, d1), m);       // fuses to v_min3_f32
    }

    __shared__ float part[4][64];
    part[w][l] = m;
    __syncthreads();

    if (w == 0) {
        float v = fminf(fminf(part[0][l], part[1][l]),
                        fminf(part[2][l], part[3][l]));
        v = fmaxf(v + p.w, 0.f);           // add |p|^2, clamp >= 0
        for (int off = 32; off; off >>= 1) v += __shfl_down(v, off);
        if (l == 0)
            atomicAdd(out, v * (0.5f / (float)CD_TOTAL));  // N == M fold
    }
}

extern "C" void kernel_launch(void* const* d_in, const int* in_sizes, int n_in,
                              void* d_out, int out_size, void* d_ws, size_t ws_size,
                              hipStream_t stream) {
    const float* recon = (const float*)d_in[0];
    const float* gt    = (const float*)d_in[1];
    float4* pts4 = (float4*)d_ws;          // 32768 float4 = 512 KB
    float* out = (float*)d_out;

    cd_prep<<<128, 256, 0, stream>>>(recon, gt, pts4, out);
    cd_main<<<512, 256, 0, stream>>>(pts4, out);
}

// Round 10
// 68.598 us; speedup vs baseline: 2.0704x; 2.0704x over previous
//
#include <hip/hip_runtime.h>

#define CD_B 4
#define CD_N 4096
#define CD_TOTAL (CD_B * CD_N)   // 16384 points per array
#define TILE 256

// ---------------- Kernel A: tiled partial mins (the heavy kernel) ----------
// Grid: 4 batches x 16 own-tiles x 16 stream-tiles = 1024 blocks, 256 thr.
// Both directions per block (the staged 256x256 tile pair serves rowmin and
// colmin). dist via |p-g|^2 = |p|^2 + (|g|^2 - 2 p.g): inner pair = 3 FMA +
// amortized min3. Lane owns 4 points (4 independent min chains); the 4 waves
// split the streamed 256 into 64 each; partials combine via LDS, then each
// thread writes ONE partial min (norm added, clamped) to a distinct pm slot —
// no atomics, no init kernel.
// pm layout: [dir][b][own_tile][stream_tile][256]  (2*4*16*16*256 floats)
__global__ __launch_bounds__(256, 4) void cd_tiles(const float* __restrict__ recon,
                                                   const float* __restrict__ gt,
                                                   float* __restrict__ pm,
                                                   float* __restrict__ out) {
    const int bid = blockIdx.x;
    const int b   = bid >> 8;
    const int ti  = (bid >> 4) & 15;
    const int tj  = bid & 15;
    const int t   = threadIdx.x;
    const int w   = t >> 6;   // wave 0..3
    const int l   = t & 63;   // lane

    if (bid == 0 && t == 0) out[0] = 0.f;   // kernel B accumulates after us

    __shared__ float4 rs[TILE];        // (x, y, z, |p|^2)
    __shared__ float4 gs[TILE];
    __shared__ float  part[4][TILE];

    {   // Stage: thread t loads point t of each tile, computes its norm.
        const float* rp = recon + ((size_t)(b * CD_N + ti * TILE) + t) * 3;
        const float* gp = gt    + ((size_t)(b * CD_N + tj * TILE) + t) * 3;
        const float rx = rp[0], ry = rp[1], rz = rp[2];
        const float gx = gp[0], gy = gp[1], gz = gp[2];
        rs[t] = make_float4(rx, ry, rz, fmaf(rz, rz, fmaf(ry, ry, rx * rx)));
        gs[t] = make_float4(gx, gy, gz, fmaf(gz, gz, fmaf(gy, gy, gx * gx)));
    }
    __syncthreads();

    const float INF = __builtin_inff();

    // ---- Phase 1 (dir 0): rowmin. Lane l owns recon rows {l,64+l,128+l,192+l};
    //      wave w streams gt cols [64w, 64w+64).
    {
        const float4 p0 = rs[l], p1 = rs[64 + l], p2 = rs[128 + l], p3 = rs[192 + l];
        const float a0x = -2.f * p0.x, a0y = -2.f * p0.y, a0z = -2.f * p0.z;
        const float a1x = -2.f * p1.x, a1y = -2.f * p1.y, a1z = -2.f * p1.z;
        const float a2x = -2.f * p2.x, a2y = -2.f * p2.y, a2z = -2.f * p2.z;
        const float a3x = -2.f * p3.x, a3y = -2.f * p3.y, a3z = -2.f * p3.z;
        float m0 = INF, m1 = INF, m2 = INF, m3 = INF;
        const int jbase = w << 6;
        #pragma unroll 8
        for (int jj = 0; jj < 64; jj += 2) {
            const float4 g0 = gs[jbase + jj];       // broadcast ds_read_b128
            const float4 g1 = gs[jbase + jj + 1];
            float d0, d1;
            d0 = fmaf(a0x, g0.x, fmaf(a0y, g0.y, fmaf(a0z, g0.z, g0.w)));
            d1 = fmaf(a0x, g1.x, fmaf(a0y, g1.y, fmaf(a0z, g1.z, g1.w)));
            m0 = fminf(fminf(d0, d1), m0);          // fuses to v_min3_f32
            d0 = fmaf(a1x, g0.x, fmaf(a1y, g0.y, fmaf(a1z, g0.z, g0.w)));
            d1 = fmaf(a1x, g1.x, fmaf(a1y, g1.y, fmaf(a1z, g1.z, g1.w)));
            m1 = fminf(fminf(d0, d1), m1);
            d0 = fmaf(a2x, g0.x, fmaf(a2y, g0.y, fmaf(a2z, g0.z, g0.w)));
            d1 = fmaf(a2x, g1.x, fmaf(a2y, g1.y, fmaf(a2z, g1.z, g1.w)));
            m2 = fminf(fminf(d0, d1), m2);
            d0 = fmaf(a3x, g0.x, fmaf(a3y, g0.y, fmaf(a3z, g0.z, g0.w)));
            d1 = fmaf(a3x, g1.x, fmaf(a3y, g1.y, fmaf(a3z, g1.z, g1.w)));
            m3 = fminf(fminf(d0, d1), m3);
        }
        part[w][l]       = m0;
        part[w][64 + l]  = m1;
        part[w][128 + l] = m2;
        part[w][192 + l] = m3;
    }
    __syncthreads();
    {   // combine wave partials for recon point t; add |p|^2; plain store
        const float v = fminf(fminf(part[0][t], part[1][t]),
                              fminf(part[2][t], part[3][t]));
        const float dist = fmaxf(v + rs[t].w, 0.f);
        // dir 0 slot: ((b*16 + ti)*16 + tj)*256 + t
        pm[(((b << 4) + ti) << 12) + (tj << 8) + t] = dist;
    }
    __syncthreads();  // part[] reused below

    // ---- Phase 2 (dir 1): colmin. Lane l owns gt cols; wave w streams recon.
    {
        const float4 q0 = gs[l], q1 = gs[64 + l], q2 = gs[128 + l], q3 = gs[192 + l];
        const float a0x = -2.f * q0.x, a0y = -2.f * q0.y, a0z = -2.f * q0.z;
        const float a1x = -2.f * q1.x, a1y = -2.f * q1.y, a1z = -2.f * q1.z;
        const float a2x = -2.f * q2.x, a2y = -2.f * q2.y, a2z = -2.f * q2.z;
        const float a3x = -2.f * q3.x, a3y = -2.f * q3.y, a3z = -2.f * q3.z;
        float m0 = INF, m1 = INF, m2 = INF, m3 = INF;
        const int ibase = w << 6;
        #pragma unroll 8
        for (int ii = 0; ii < 64; ii += 2) {
            const float4 r0 = rs[ibase + ii];
            const float4 r1 = rs[ibase + ii + 1];
            float d0, d1;
            d0 = fmaf(a0x, r0.x, fmaf(a0y, r0.y, fmaf(a0z, r0.z, r0.w)));
            d1 = fmaf(a0x, r1.x, fmaf(a0y, r1.y, fmaf(a0z, r1.z, r1.w)));
            m0 = fminf(fminf(d0, d1), m0);
            d0 = fmaf(a1x, r0.x, fmaf(a1y, r0.y, fmaf(a1z, r0.z, r0.w)));
            d1 = fmaf(a1x, r1.x, fmaf(a1y, r1.y, fmaf(a1z, r1.z, r1.w)));
            m1 = fminf(fminf(d0, d1), m1);
            d0 = fmaf(a2x, r0.x, fmaf(a2y, r0.y, fmaf(a2z, r0.z, r0.w)));
            d1 = fmaf(a2x, r1.x, fmaf(a2y, r1.y, fmaf(a2z, r1.z, r1.w)));
            m2 = fminf(fminf(d0, d1), m2);
            d0 = fmaf(a3x, r0.x, fmaf(a3y, r0.y, fmaf(a3z, r0.z, r0.w)));
            d1 = fmaf(a3x, r1.x, fmaf(a3y, r1.y, fmaf(a3z, r1.z, r1.w)));
            m3 = fminf(fminf(d0, d1), m3);
        }
        part[w][l]       = m0;
        part[w][64 + l]  = m1;
        part[w][128 + l] = m2;
        part[w][192 + l] = m3;
    }
    __syncthreads();
    {   // combine wave partials for gt point t; add |g|^2; plain store
        const float v = fminf(fminf(part[0][t], part[1][t]),
                              fminf(part[2][t], part[3][t]));
        const float dist = fmaxf(v + gs[t].w, 0.f);
        // dir 1 slot: 262144 + ((b*16 + tj)*16 + ti)*256 + t
        pm[262144 + (((b << 4) + tj) << 12) + (ti << 8) + t] = dist;
    }
}

// ---------------- Kernel B: gather 16 partials per point, sum, accumulate ---
// 128 blocks x 256 threads = 32768 threads, one per (dir, b, own_tile, p).
// 16 loads at stride 256 floats (each is a coalesced 256B wave read), 15 mins,
// block reduction, one scaled atomicAdd per block (128 total).
__global__ __launch_bounds__(256) void cd_gather(const float* __restrict__ pm,
                                                 float* __restrict__ out) {
    const int tid = blockIdx.x * 256 + threadIdx.x;  // [0, 32768)
    const int p   = tid & 255;
    const int ot  = (tid >> 8) & 15;
    const int gb  = tid >> 12;                       // dir*4 + b, [0,8)
    const float* base = pm + ((((gb << 4) + ot) << 4) << 8) + p;

    float m = base[0];
    #pragma unroll
    for (int st = 1; st < 16; ++st) m = fminf(m, base[st << 8]);

    // block sum reduction
    for (int off = 32; off; off >>= 1) m += __shfl_down(m, off);
    __shared__ float ws[4];
    const int t = threadIdx.x;
    if ((t & 63) == 0) ws[t >> 6] = m;
    __syncthreads();
    if (t == 0) {
        const float s = ws[0] + ws[1] + ws[2] + ws[3];
        // loss = (mean1 + mean2) / 2 = totalsum * 0.5 / CD_TOTAL
        atomicAdd(out, s * (0.5f / (float)CD_TOTAL));
    }
}

extern "C" void kernel_launch(void* const* d_in, const int* in_sizes, int n_in,
                              void* d_out, int out_size, void* d_ws, size_t ws_size,
                              hipStream_t stream) {
    const float* recon = (const float*)d_in[0];
    const float* gt    = (const float*)d_in[1];
    float* pm  = (float*)d_ws;     // 2*4*16*16*256 floats = 2 MB
    float* out = (float*)d_out;

    cd_tiles<<<CD_B * 16 * 16, 256, 0, stream>>>(recon, gt, pm, out);
    cd_gather<<<128, 256, 0, stream>>>(pm, out);
}